// Round 2
// baseline (220.727 us; speedup 1.0000x reference)
//
#include <hip/hip_runtime.h>

#define NROWS 8192
#define BQ    4096
#define DDIM  256
#define INV_T (1.0f/0.07f)
#define K2EXP (1.4426950408889634f/0.07f)   // log2(e)/T

typedef short bf16x8 __attribute__((ext_vector_type(8)));
typedef float f32x4  __attribute__((ext_vector_type(4)));
typedef unsigned short u16;

__device__ __forceinline__ u16 f2bf(float f) {
  unsigned u = __float_as_uint(f);
  u += 0x7fffu + ((u >> 16) & 1u);   // round-to-nearest-even
  return (u16)(u >> 16);
}

// ---------------- kernel 1: L2-normalize rows of [z_i; z_j], cast to bf16 ----
__global__ void norm_cast_kernel(const float* __restrict__ zi,
                                 const float* __restrict__ zj,
                                 u16* __restrict__ zb) {
  int wave = threadIdx.x >> 6;
  int lane = threadIdx.x & 63;
  int row  = blockIdx.x * 4 + wave;            // one wave per row, 4 rows/block
  const float* src = (row < BQ) ? (zi + (size_t)row * DDIM)
                                : (zj + (size_t)(row - BQ) * DDIM);
  float4 v = ((const float4*)src)[lane];       // 64 lanes x float4 = 256
  float s = v.x*v.x + v.y*v.y + v.z*v.z + v.w*v.w;
  #pragma unroll
  for (int m = 32; m; m >>= 1) s += __shfl_xor(s, m, 64);
  float scale = 1.0f / fmaxf(sqrtf(s), 1e-12f);
  ushort4 o;
  o.x = f2bf(v.x * scale); o.y = f2bf(v.y * scale);
  o.z = f2bf(v.z * scale); o.w = f2bf(v.w * scale);
  ((ushort4*)(zb + (size_t)row * DDIM))[lane] = o;
}

// ---------------- kernel 2: fused sim GEMM + mask + pos/negexp row partials --
#define GL2LDS(gp, lp) \
  __builtin_amdgcn_global_load_lds((__attribute__((address_space(1))) void*)(gp), \
                                   (__attribute__((address_space(3))) void*)(lp), 16, 0, 0)

__global__ __launch_bounds__(256, 4) void simloss_kernel(
    const u16* __restrict__ zb, const int* __restrict__ labels,
    float* __restrict__ pos_p, float* __restrict__ neg_p) {
  // row-major [128][32] bf16, chunk-SWIZZLED: row r's 8-elt chunk c lives at
  // slot c ^ ((r>>1)&3). Banks repeat every 2 rows (128B), so keying on r>>1
  // spreads each quad's 16 lanes over all 16 bank-groups -> 2-way = free.
  __shared__ __align__(16) u16 lsA[128 * 32];
  __shared__ __align__(16) u16 lsB[128 * 32];

  const int tid  = threadIdx.x;
  const int w    = tid >> 6;         // wave 0..3
  const int lane = tid & 63;
  const int ln   = lane & 15;        // MFMA n/m lane index
  const int qd   = lane >> 4;        // MFMA quad
  const int wr   = w >> 1;           // wave row (0..1) in 2x2 wave grid
  const int wc   = w & 1;            // wave col
  const int r0   = blockIdx.x * 128; // block row base (64 row tiles)
  const int cb   = blockIdx.y * 512; // col split base (16 splits)

  const int strow = lane >> 2;       // staging: 16 rows per load instr
  const int slot  = lane & 3;        // LDS chunk position this lane fills
  const int stk   = (slot ^ ((strow >> 1) & 3)) * 8;  // global chunk to fetch
  const int rdsw  = (ln >> 1) & 3;   // read-side swizzle key

  int rowidx[16], rowlab[16];
  #pragma unroll
  for (int ri = 0; ri < 4; ++ri)
    #pragma unroll
    for (int r = 0; r < 4; ++r) {
      int slt = ri * 4 + r;
      int row = r0 + wr * 64 + ri * 16 + qd * 4 + r;   // C/D: row = quad*4+reg
      rowidx[slt] = row;
      rowlab[slt] = labels[row & (BQ - 1)];            // concat labels = labels[row % B]
    }

  float posA[16], negA[16];
  #pragma unroll
  for (int i = 0; i < 16; ++i) { posA[i] = 0.0f; negA[i] = 0.0f; }

  for (int ci = 0; ci < 4; ++ci) {               // 4 x 128 cols per block
    const int c0 = cb + ci * 128;
    int colv[4], clab[4];
    #pragma unroll
    for (int mi = 0; mi < 4; ++mi) {
      colv[mi] = c0 + wc * 64 + mi * 16 + ln;    // C/D: col = lane&15
      clab[mi] = labels[colv[mi] & (BQ - 1)];
    }

    const f32x4 z4 = {0.f, 0.f, 0.f, 0.f};
    f32x4 acc[4][4];
    #pragma unroll
    for (int ri = 0; ri < 4; ++ri)
      #pragma unroll
      for (int mi = 0; mi < 4; ++mi) acc[ri][mi] = z4;

    for (int kk = 0; kk < 8; ++kk) {             // K = 256, BK = 32
      const int k0 = kk * 32;
      #pragma unroll
      for (int j = 0; j < 2; ++j) {              // wave stages 32 rows of A and B
        int rbase = w * 32 + j * 16;
        const u16* ga = zb + (size_t)(r0 + rbase + strow) * DDIM + k0 + stk;
        GL2LDS(ga, &lsA[rbase * 32]);
        const u16* gb = zb + (size_t)(c0 + rbase + strow) * DDIM + k0 + stk;
        GL2LDS(gb, &lsB[rbase * 32]);
      }
      __syncthreads();                           // drains vmcnt before barrier

      bf16x8 av[4], bv[4];
      #pragma unroll
      for (int ri = 0; ri < 4; ++ri)             // A[m=ln][k=qd*8+j], swizzled slot
        av[ri] = *(const bf16x8*)&lsA[(wr * 64 + ri * 16 + ln) * 32 + (qd ^ rdsw) * 8];
      #pragma unroll
      for (int mi = 0; mi < 4; ++mi)             // B[n=ln][k=qd*8+j] (B^T input)
        bv[mi] = *(const bf16x8*)&lsB[(wc * 64 + mi * 16 + ln) * 32 + (qd ^ rdsw) * 8];
      #pragma unroll
      for (int ri = 0; ri < 4; ++ri)
        #pragma unroll
        for (int mi = 0; mi < 4; ++mi)
          acc[ri][mi] = __builtin_amdgcn_mfma_f32_16x16x32_bf16(
              av[ri], bv[mi], acc[ri][mi], 0, 0, 0);
      __syncthreads();
    }

    // fused epilogue: mask + accumulate per-row pos (raw dot) and neg (exp)
    #pragma unroll
    for (int ri = 0; ri < 4; ++ri)
      #pragma unroll
      for (int mi = 0; mi < 4; ++mi) {
        f32x4 v = acc[ri][mi];
        #pragma unroll
        for (int r = 0; r < 4; ++r) {
          int slt = ri * 4 + r;
          float s = v[r];
          bool same = (rowlab[slt] == clab[mi]);
          bool diag = (rowidx[slt] == colv[mi]);
          posA[slt] += (same && !diag) ? s : 0.0f;
          negA[slt] += same ? 0.0f : __builtin_amdgcn_exp2f(s * K2EXP);
        }
      }
  }

  // reduce over the 16 lanes (ln) that hold different cols of the same row
  #pragma unroll
  for (int i = 0; i < 16; ++i) {
    #pragma unroll
    for (int m = 1; m < 16; m <<= 1) {
      posA[i] += __shfl_xor(posA[i], m, 64);
      negA[i] += __shfl_xor(negA[i], m, 64);
    }
  }

  // combine the two wc halves through LDS so slices stay at 16 (ws budget)
  __syncthreads();                               // all waves done reading lsA/lsB
  float* scp = (float*)lsA;                      // [2][128] pos
  float* scn = (float*)lsB;                      // [2][128] neg
  if (ln == 0) {
    #pragma unroll
    for (int i = 0; i < 16; ++i) {
      int lr = rowidx[i] - r0;                   // 0..127
      scp[wc * 128 + lr] = posA[i];
      scn[wc * 128 + lr] = negA[i];
    }
  }
  __syncthreads();
  if (tid < 128) {
    float p = scp[tid] + scp[128 + tid];
    float n = scn[tid] + scn[128 + tid];
    pos_p[(size_t)blockIdx.y * NROWS + r0 + tid] = p;
    neg_p[(size_t)blockIdx.y * NROWS + r0 + tid] = n;
  }
}

// ---------------- kernel 3: per-row loss + mean (parallel, atomic) -----------
__global__ void loss_kernel(const float* __restrict__ pos_p,
                            const float* __restrict__ neg_p,
                            float* __restrict__ out) {
  int row = blockIdx.x * 256 + threadIdx.x;      // 32 blocks x 256 threads
  float p = 0.0f, n = 0.0f;
  #pragma unroll
  for (int s = 0; s < 16; ++s) {
    p += pos_p[(size_t)s * NROWS + row];
    n += neg_p[(size_t)s * NROWS + row];
  }
  float l = log1pf(expf(logf(n) - p * INV_T));
  #pragma unroll
  for (int m = 32; m; m >>= 1) l += __shfl_xor(l, m, 64);
  __shared__ float red[4];
  if ((threadIdx.x & 63) == 0) red[threadIdx.x >> 6] = l;
  __syncthreads();
  if (threadIdx.x == 0) {
    float tot = red[0] + red[1] + red[2] + red[3];
    atomicAdd(out, tot * (1.0f / NROWS));
  }
}

// ---------------- launcher ---------------------------------------------------
extern "C" void kernel_launch(void* const* d_in, const int* in_sizes, int n_in,
                              void* d_out, int out_size, void* d_ws, size_t ws_size,
                              hipStream_t stream) {
  const float* zi     = (const float*)d_in[0];
  const float* zj     = (const float*)d_in[1];
  const int*   labels = (const int*)d_in[2];
  float*       out    = (float*)d_out;

  char* w = (char*)d_ws;
  u16*   zb    = (u16*)w;                                          // 4 MB bf16 Z
  float* pos_p = (float*)(w + (size_t)NROWS * DDIM * sizeof(u16)); // 16x8192 f32
  float* neg_p = pos_p + 16 * NROWS;                               // 16x8192 f32

  hipMemsetAsync(out, 0, sizeof(float), stream);                   // atomic target
  hipLaunchKernelGGL(norm_cast_kernel, dim3(2048), dim3(256), 0, stream, zi, zj, zb);
  hipLaunchKernelGGL(simloss_kernel, dim3(64, 16), dim3(256), 0, stream,
                     zb, labels, pos_p, neg_p);
  hipLaunchKernelGGL(loss_kernel, dim3(32), dim3(256), 0, stream,
                     pos_p, neg_p, out);
}

// Round 3
// 121.628 us; speedup vs baseline: 1.8148x; 1.8148x over previous
//
#include <hip/hip_runtime.h>

#define NROWS 8192
#define BQ    4096
#define DDIM  256
#define INV_T (1.0f/0.07f)
#define K2EXP (1.4426950408889634f/0.07f)   // log2(e)/T

typedef short bf16x8 __attribute__((ext_vector_type(8)));
typedef float f32x4  __attribute__((ext_vector_type(4)));
typedef unsigned short u16;

__device__ __forceinline__ u16 f2bf(float f) {
  unsigned u = __float_as_uint(f);
  u += 0x7fffu + ((u >> 16) & 1u);   // round-to-nearest-even
  return (u16)(u >> 16);
}

// ---------------- kernel 1: L2-normalize rows of [z_i; z_j], cast to bf16 ----
__global__ void norm_cast_kernel(const float* __restrict__ zi,
                                 const float* __restrict__ zj,
                                 u16* __restrict__ zb) {
  int wave = threadIdx.x >> 6;
  int lane = threadIdx.x & 63;
  int row  = blockIdx.x * 4 + wave;            // one wave per row, 4 rows/block
  const float* src = (row < BQ) ? (zi + (size_t)row * DDIM)
                                : (zj + (size_t)(row - BQ) * DDIM);
  float4 v = ((const float4*)src)[lane];       // 64 lanes x float4 = 256
  float s = v.x*v.x + v.y*v.y + v.z*v.z + v.w*v.w;
  #pragma unroll
  for (int m = 32; m; m >>= 1) s += __shfl_xor(s, m, 64);
  float scale = 1.0f / fmaxf(sqrtf(s), 1e-12f);
  ushort4 o;
  o.x = f2bf(v.x * scale); o.y = f2bf(v.y * scale);
  o.z = f2bf(v.z * scale); o.w = f2bf(v.w * scale);
  ((ushort4*)(zb + (size_t)row * DDIM))[lane] = o;
}

// ---------------- kernel 2: fused sim GEMM + mask + pos/negexp row partials --
#define GL2LDS(gp, lp) \
  __builtin_amdgcn_global_load_lds((__attribute__((address_space(1))) void*)(gp), \
                                   (__attribute__((address_space(3))) void*)(lp), 16, 0, 0)

// NOTE: __launch_bounds__(256) ONLY — adding a min-waves arg of 4 (round 2)
// capped the unified VGPR+AGPR file at 128/wave, spilled the 64-AGPR
// accumulator to scratch, and generated 620 MB of HBM spill traffic
// (63us -> 160us). Do not re-add.
__global__ __launch_bounds__(256) void simloss_kernel(
    const u16* __restrict__ zb, const int* __restrict__ labels,
    float* __restrict__ pos_p, float* __restrict__ neg_p) {
  // row-major [128][32] bf16, chunk-SWIZZLED: row r's 8-elt chunk c lives at
  // slot c ^ ((r>>1)&3). Banks repeat every 2 rows (128B), so keying on r>>1
  // spreads each quad's 16 lanes over all 16 bank-groups -> 2-way = free.
  // (measured round 2: SQ_LDS_BANK_CONFLICT 4.19M -> 0)
  __shared__ __align__(16) u16 lsA[128 * 32];
  __shared__ __align__(16) u16 lsB[128 * 32];

  const int tid  = threadIdx.x;
  const int w    = tid >> 6;         // wave 0..3
  const int lane = tid & 63;
  const int ln   = lane & 15;        // MFMA n/m lane index
  const int qd   = lane >> 4;        // MFMA quad
  const int wr   = w >> 1;           // wave row (0..1) in 2x2 wave grid
  const int wc   = w & 1;            // wave col
  const int r0   = blockIdx.x * 128; // block row base (64 row tiles)
  const int cb   = blockIdx.y * 1024;// col split base (8 splits)

  const int strow = lane >> 2;       // staging: 16 rows per load instr
  const int slot  = lane & 3;        // LDS chunk position this lane fills
  const int stk   = (slot ^ ((strow >> 1) & 3)) * 8;  // global chunk to fetch
  const int rdsw  = (ln >> 1) & 3;   // read-side swizzle key

  int rowidx[16], rowlab[16];
  #pragma unroll
  for (int ri = 0; ri < 4; ++ri)
    #pragma unroll
    for (int r = 0; r < 4; ++r) {
      int slt = ri * 4 + r;
      int row = r0 + wr * 64 + ri * 16 + qd * 4 + r;   // C/D: row = quad*4+reg
      rowidx[slt] = row;
      rowlab[slt] = labels[row & (BQ - 1)];            // concat labels = labels[row % B]
    }

  float posA[16], negA[16];
  #pragma unroll
  for (int i = 0; i < 16; ++i) { posA[i] = 0.0f; negA[i] = 0.0f; }

  for (int ci = 0; ci < 8; ++ci) {               // 8 x 128 cols per block
    const int c0 = cb + ci * 128;
    int colv[4], clab[4];
    #pragma unroll
    for (int mi = 0; mi < 4; ++mi) {
      colv[mi] = c0 + wc * 64 + mi * 16 + ln;    // C/D: col = lane&15
      clab[mi] = labels[colv[mi] & (BQ - 1)];
    }

    const f32x4 z4 = {0.f, 0.f, 0.f, 0.f};
    f32x4 acc[4][4];
    #pragma unroll
    for (int ri = 0; ri < 4; ++ri)
      #pragma unroll
      for (int mi = 0; mi < 4; ++mi) acc[ri][mi] = z4;

    for (int kk = 0; kk < 8; ++kk) {             // K = 256, BK = 32
      const int k0 = kk * 32;
      #pragma unroll
      for (int j = 0; j < 2; ++j) {              // wave stages 32 rows of A and B
        int rbase = w * 32 + j * 16;
        const u16* ga = zb + (size_t)(r0 + rbase + strow) * DDIM + k0 + stk;
        GL2LDS(ga, &lsA[rbase * 32]);
        const u16* gb = zb + (size_t)(c0 + rbase + strow) * DDIM + k0 + stk;
        GL2LDS(gb, &lsB[rbase * 32]);
      }
      __syncthreads();                           // drains vmcnt before barrier

      bf16x8 av[4], bv[4];
      #pragma unroll
      for (int ri = 0; ri < 4; ++ri)             // A[m=ln][k=qd*8+j], swizzled slot
        av[ri] = *(const bf16x8*)&lsA[(wr * 64 + ri * 16 + ln) * 32 + (qd ^ rdsw) * 8];
      #pragma unroll
      for (int mi = 0; mi < 4; ++mi)             // B[n=ln][k=qd*8+j] (B^T input)
        bv[mi] = *(const bf16x8*)&lsB[(wc * 64 + mi * 16 + ln) * 32 + (qd ^ rdsw) * 8];
      #pragma unroll
      for (int ri = 0; ri < 4; ++ri)
        #pragma unroll
        for (int mi = 0; mi < 4; ++mi)
          acc[ri][mi] = __builtin_amdgcn_mfma_f32_16x16x32_bf16(
              av[ri], bv[mi], acc[ri][mi], 0, 0, 0);
      __syncthreads();
    }

    // fused epilogue: mask + accumulate per-row pos (raw dot) and neg (exp)
    #pragma unroll
    for (int ri = 0; ri < 4; ++ri)
      #pragma unroll
      for (int mi = 0; mi < 4; ++mi) {
        f32x4 v = acc[ri][mi];
        #pragma unroll
        for (int r = 0; r < 4; ++r) {
          int slt = ri * 4 + r;
          float s = v[r];
          bool same = (rowlab[slt] == clab[mi]);
          bool diag = (rowidx[slt] == colv[mi]);
          posA[slt] += (same && !diag) ? s : 0.0f;
          negA[slt] += same ? 0.0f : __builtin_amdgcn_exp2f(s * K2EXP);
        }
      }
  }

  // reduce over the 16 lanes (ln) that hold different cols of the same row
  #pragma unroll
  for (int i = 0; i < 16; ++i) {
    #pragma unroll
    for (int m = 1; m < 16; m <<= 1) {
      posA[i] += __shfl_xor(posA[i], m, 64);
      negA[i] += __shfl_xor(negA[i], m, 64);
    }
  }
  if (ln == 0) {
    int s = blockIdx.y * 2 + wc;                 // 16 disjoint slices
    #pragma unroll
    for (int i = 0; i < 16; ++i) {
      pos_p[(size_t)s * NROWS + rowidx[i]] = posA[i];
      neg_p[(size_t)s * NROWS + rowidx[i]] = negA[i];
    }
  }
}

// ---------------- kernel 3: per-row loss + mean (parallel, atomic) -----------
__global__ void loss_kernel(const float* __restrict__ pos_p,
                            const float* __restrict__ neg_p,
                            float* __restrict__ out) {
  int row = blockIdx.x * 256 + threadIdx.x;      // 32 blocks x 256 threads
  float p = 0.0f, n = 0.0f;
  #pragma unroll
  for (int s = 0; s < 16; ++s) {
    p += pos_p[(size_t)s * NROWS + row];
    n += neg_p[(size_t)s * NROWS + row];
  }
  float l = log1pf(expf(logf(n) - p * INV_T));
  #pragma unroll
  for (int m = 32; m; m >>= 1) l += __shfl_xor(l, m, 64);
  __shared__ float red[4];
  if ((threadIdx.x & 63) == 0) red[threadIdx.x >> 6] = l;
  __syncthreads();
  if (threadIdx.x == 0) {
    float tot = red[0] + red[1] + red[2] + red[3];
    atomicAdd(out, tot * (1.0f / NROWS));
  }
}

// ---------------- launcher ---------------------------------------------------
extern "C" void kernel_launch(void* const* d_in, const int* in_sizes, int n_in,
                              void* d_out, int out_size, void* d_ws, size_t ws_size,
                              hipStream_t stream) {
  const float* zi     = (const float*)d_in[0];
  const float* zj     = (const float*)d_in[1];
  const int*   labels = (const int*)d_in[2];
  float*       out    = (float*)d_out;

  char* w = (char*)d_ws;
  u16*   zb    = (u16*)w;                                          // 4 MB bf16 Z
  float* pos_p = (float*)(w + (size_t)NROWS * DDIM * sizeof(u16)); // 16x8192 f32
  float* neg_p = pos_p + 16 * NROWS;                               // 16x8192 f32

  hipMemsetAsync(out, 0, sizeof(float), stream);                   // atomic target
  hipLaunchKernelGGL(norm_cast_kernel, dim3(2048), dim3(256), 0, stream, zi, zj, zb);
  hipLaunchKernelGGL(simloss_kernel, dim3(64, 8), dim3(256), 0, stream,
                     zb, labels, pos_p, neg_p);
  hipLaunchKernelGGL(loss_kernel, dim3(32), dim3(256), 0, stream,
                     pos_p, neg_p, out);
}